// Round 20
// baseline (318.956 us; speedup 1.0000x reference)
//
#include <hip/hip_runtime.h>
#include <hip/hip_bf16.h>
#include <math.h>

#define N_NODES 10000
#define KE 31
#define SD 8
#define ID 2
#define ZD 32
#define ED 64
#define HH 128
#define FC 128
#define AT 16
#define FT 6
#define DT_C 0.25f
#define NB 4           // nodes per edge_att block

#define NTU 40         // real nodes per node_update block: grid = 250 (measured best)
#define MT 3           // M-tiles (48 rows, 8 pad)

#define NKS_O 6        // obs LSTM K=192 = 6*32
#define NKS_S 5        // st LSTM  K=160 = 5*32
#define NKS_A 10       // act1     K=320 = 10*32

// packed-weight sizes (uints)
#define WP_OBS_SZ 49152
#define WP_ST_SZ  40960
#define WP_ACT_SZ 20480
#define WP_EDGE_SZ 1024
#define WP_ATT1_SZ 512

typedef __bf16 bf16x8 __attribute__((ext_vector_type(8)));
typedef float  f32x4  __attribute__((ext_vector_type(4)));

__device__ __forceinline__ float sigm(float x){ return 1.0f/(1.0f+exp2f(-1.44269504f*x)); }
__device__ __forceinline__ float tanh_f(float x){ return 1.0f - 2.0f/(1.0f+exp2f(2.88539008f*x)); }

__device__ __forceinline__ unsigned short f2b(float f){
  __hip_bfloat16 h = __float2bfloat16(f);
  return __builtin_bit_cast(unsigned short, h);
}
__device__ __forceinline__ float b2f(unsigned short x){
  unsigned int u = ((unsigned int)x) << 16;
  return __builtin_bit_cast(float, u);
}
__device__ __forceinline__ unsigned int pack2(float a, float b){
  return (unsigned int)f2b(a) | ((unsigned int)f2b(b) << 16);
}
__device__ __forceinline__ bf16x8 as_bf16x8(int4 v){
  union { int4 i; bf16x8 b; } u; u.i = v; return u.b;
}
__device__ __forceinline__ int hwaddr(int e, int d){
  return e*64 + ((((d>>3)<<3) ^ ((e&7)<<3)) + (d&7));
}
// wtile-major state layout: x[(h>>4)*N*16 + n*16 + (h&15)] — wave epilogue = full 128B lines
__device__ __forceinline__ int sidx(int n, int h){
  return ((h>>4)*N_NODES + n)*16 + (h&15);
}

// ---------------- pack_weights (unchanged layout) ----------------
__global__ __launch_bounds__(256) void pack_weights(
    const float* __restrict__ obs_Wi, const float* __restrict__ obs_Wh,
    const float* __restrict__ st_Wi,  const float* __restrict__ st_Wh,
    const float* __restrict__ act_W1, const float* __restrict__ W_edge,
    const float* __restrict__ att_W1,
    unsigned int* __restrict__ wp_obs, unsigned int* __restrict__ wp_st,
    unsigned int* __restrict__ wp_act, unsigned int* __restrict__ wp_edge,
    unsigned int* __restrict__ wp_att1)
{
  int t = blockIdx.x*256 + threadIdx.x;
  if (t < 49152){
    int c = t / 1536; int r = t - c*1536;
    int ks = r >> 8; int q = r & 255;
    int ln = q >> 2; int dw = q & 3;
    int k  = ks*32 + ((ln>>4)<<3) + dw*2;
    int col = (c<<4) + (ln & 15);
    float v0 = (k   < 64) ? obs_Wi[k*4*HH + col]      : obs_Wh[(k-64)*4*HH + col];
    float v1 = (k+1 < 64) ? obs_Wi[(k+1)*4*HH + col]  : obs_Wh[(k-63)*4*HH + col];
    wp_obs[t] = pack2(v0, v1);
  } else if (t < 90112){
    int t2 = t - 49152;
    int c = t2 / 1280; int r = t2 - c*1280;
    int ks = r >> 8; int q = r & 255;
    int ln = q >> 2; int dw = q & 3;
    int k  = ks*32 + ((ln>>4)<<3) + dw*2;
    int col = (c<<4) + (ln & 15);
    float v0, v1;
    { int kk=k;   v0 = (kk<10)? st_Wi[kk*4*HH+col] : (kk<138 ? st_Wh[(kk-10)*4*HH+col] : 0.f); }
    { int kk=k+1; v1 = (kk<10)? st_Wi[kk*4*HH+col] : (kk<138 ? st_Wh[(kk-10)*4*HH+col] : 0.f); }
    wp_st[t2] = pack2(v0, v1);
  } else if (t < 110592){
    int t3 = t - 90112;
    int c = t3 / 2560; int r = t3 - c*2560;
    int ks = r >> 8; int q = r & 255;
    int ln = q >> 2; int dw = q & 3;
    int k  = ks*32 + ((ln>>4)<<3) + dw*2;
    int col = (c<<4) + (ln & 15);
    float v0 = (k   < 296) ? act_W1[k*FC + col]     : 0.f;
    float v1 = (k+1 < 296) ? act_W1[(k+1)*FC + col] : 0.f;
    wp_act[t3] = pack2(v0, v1);
  } else if (t < 111616){
    int t4 = t - 110592;
    int c = t4 >> 8; int r = t4 & 255;
    int ln = r >> 2; int dw = r & 3;
    int k  = ((ln>>4)<<3) + dw*2;
    int col = (c<<4) + (ln & 15);
    float v0 = (k   < 16) ? W_edge[k*ED + col]     : 0.f;
    float v1 = (k+1 < 16) ? W_edge[(k+1)*ED + col] : 0.f;
    wp_edge[t4] = pack2(v0, v1);
  } else if (t < 112128){
    int t5 = t - 111616;
    int ks = t5 >> 8; int r = t5 & 255;
    int ln = r >> 2; int dw = r & 3;
    int k  = ks*32 + ((ln>>4)<<3) + dw*2;
    int col = ln & 15;
    float v0 = (k   < 64) ? att_W1[k*AT + col]     : 0.f;
    float v1 = (k+1 < 64) ? att_W1[(k+1)*AT + col] : 0.f;
    wp_att1[t5] = pack2(v0, v1);
  }
}

// ---------------- init: states bf16 in wtile-major layout; s0 bf16 mirror ----------------
__global__ __launch_bounds__(256) void init_kernel(
    const float* __restrict__ s0,
    const float* __restrict__ oh0_W, const float* __restrict__ oh0_b,
    const float* __restrict__ oc0_W, const float* __restrict__ oc0_b,
    const float* __restrict__ sh0_W, const float* __restrict__ sh0_b,
    const float* __restrict__ sc0_W, const float* __restrict__ sc0_b,
    unsigned short* __restrict__ oh, unsigned short* __restrict__ oc,
    unsigned short* __restrict__ sh, unsigned short* __restrict__ sc,
    float* __restrict__ u, unsigned short* __restrict__ s0bf)
{
  int t = blockIdx.x*256 + threadIdx.x;
  if (t < N_NODES*ID) u[t] = 0.0f;
  if (t < N_NODES*SD) s0bf[t] = f2b(s0[t]);
  if (t >= N_NODES*HH) return;
  int n = t >> 7, j = t & 127;
  float s[SD];
  #pragma unroll
  for (int i=0;i<SD;i++) s[i] = s0[n*SD+i];
  float a0=oh0_b[j], a1=oc0_b[j], a2=sh0_b[j], a3=sc0_b[j];
  #pragma unroll
  for (int i=0;i<SD;i++){
    a0 = fmaf(s[i], oh0_W[i*HH+j], a0);
    a1 = fmaf(s[i], oc0_W[i*HH+j], a1);
    a2 = fmaf(s[i], sh0_W[i*HH+j], a2);
    a3 = fmaf(s[i], sc0_W[i*HH+j], a3);
  }
  int p = sidx(n, j);
  oh[p]=f2b(a0); oc[p]=f2b(a1); sh[p]=f2b(a2); sc[p]=f2b(a3);
}

// ---------------- K1: edge encode + attention; endpoint gather bf16; ctx wtile-major ----------------
__global__ __launch_bounds__(256) void edge_att_mfma(
    const float* __restrict__ s_prev, const float* __restrict__ s0,
    const unsigned short* __restrict__ sprev_bf,
    const int* __restrict__ edge_idx1, const int* __restrict__ edge_idx2,
    const int* __restrict__ node_obs_idx,
    const unsigned int* __restrict__ wp_edge, const unsigned int* __restrict__ wp_att1,
    const float* __restrict__ b_edge, const float* __restrict__ att_W2,
    const float* __restrict__ att_v, unsigned short* __restrict__ ctx)
{
  __shared__ __align__(16) unsigned int eF[8*64*4];
  __shared__ __align__(16) unsigned short encL[128*64];
  __shared__ __align__(16) unsigned int pF[4*64*4];
  __shared__ float scores[128];
  __shared__ float relbuf[NB][SD];
  __shared__ float relW2b[NB][AT];
  __shared__ unsigned char emask[128];

  const int tid  = threadIdx.x;
  const int lane = tid & 63;
  const int w    = tid >> 6;
  const int n0   = blockIdx.x * NB;
  const int EPB  = NB*KE;

  {
    ((uint4*)pF)[tid] = (uint4){0,0,0,0};
    int eb  = tid >> 1;
    int khi = tid & 1;
    int valid = 0;
    uint4 d = (uint4){0,0,0,0};
    if (eb < EPB){
      int nl = eb / KE;
      int j  = eb - nl*KE;
      int idx = node_obs_idx[(n0+nl)*KE + j];
      if (idx > 0){
        valid = 1;
        int e = idx - 1;
        int i = khi ? edge_idx2[e] : edge_idx1[e];
        d = *(const uint4*)&sprev_bf[i*SD];
      }
    }
    int mt = eb >> 4;
    int base = ((mt<<6) + (eb&15) + (khi<<4)) << 2;
    ((uint4*)&eF[base])[0] = d;
    int zbase = ((mt<<6) + (eb&15) + ((khi+2)<<4)) << 2;
    ((uint4*)&eF[zbase])[0] = (uint4){0,0,0,0};
    if (khi == 0) emask[eb] = (unsigned char)valid;
    if (tid < NB*SD){
      int m = tid >> 3, i = tid & 7;
      relbuf[m][i] = s_prev[(n0+m)*SD + i] - s0[(n0+m)*SD + i];
    }
  }
  __syncthreads();

  if (tid < NB*AT){
    int m = tid >> 4, a = tid & 15;
    float acc = 0.f;
    #pragma unroll
    for (int i = 0; i < SD; ++i) acc = fmaf(relbuf[m][i], att_W2[i*AT + a], acc);
    relW2b[m][a] = acc;
  }
  {
    const int c = lane & 15, g = lane >> 4;
    #pragma unroll
    for (int q = 0; q < 2; ++q){
      int mt = w*2 + q;
      bf16x8 A = as_bf16x8(*(const int4*)&eF[((mt<<6) + lane) << 2]);
      f32x4 acc[4];
      #pragma unroll
      for (int ct = 0; ct < 4; ++ct){
        bf16x8 B = as_bf16x8(*(const int4*)&wp_edge[((ct<<6) + lane) << 2]);
        acc[ct] = (f32x4){0,0,0,0};
        acc[ct] = __builtin_amdgcn_mfma_f32_16x16x32_bf16(A, B, acc[ct], 0, 0, 0);
      }
      #pragma unroll
      for (int ct = 0; ct < 4; ++ct){
        int d = ct*16 + c;
        float bias = b_edge[d];
        #pragma unroll
        for (int r = 0; r < 4; ++r){
          int eb = mt*16 + g*4 + r;
          float v = acc[ct][r] + bias;
          v = emask[eb] ? fmaxf(v, 0.f) : 0.f;
          encL[hwaddr(eb, d)] = f2b(v);
        }
      }
    }
  }
  __syncthreads();

  {
    const int c = lane & 15, g = lane >> 4;
    const float av = att_v[c];
    #pragma unroll
    for (int q = 0; q < 2; ++q){
      int mt = w*2 + q;
      int row = mt*16 + c;
      f32x4 acc = (f32x4){0,0,0,0};
      #pragma unroll
      for (int ks = 0; ks < 2; ++ks){
        int hw = row*64 + (((ks*4 + g) << 3) ^ ((row&7) << 3));
        bf16x8 A = *(const bf16x8*)&encL[hw];
        bf16x8 B = as_bf16x8(*(const int4*)&wp_att1[((ks<<6) + lane) << 2]);
        acc = __builtin_amdgcn_mfma_f32_16x16x32_bf16(A, B, acc, 0, 0, 0);
      }
      #pragma unroll
      for (int r = 0; r < 4; ++r){
        int eb = mt*16 + g*4 + r;
        int nm = eb / KE; if (nm > NB-1) nm = NB-1;
        float sv = av * tanh_f(acc[r] + relW2b[nm][c]);
        #pragma unroll
        for (int off = 1; off < 16; off <<= 1) sv += __shfl_xor(sv, off);
        if (c == 0 && eb < EPB) scores[eb] = sv;
      }
    }
  }
  __syncthreads();

  {
    int m = w;
    float sc_ = (lane < KE) ? scores[m*KE + lane] : -INFINITY;
    float mx = sc_;
    #pragma unroll
    for (int off = 32; off; off >>= 1) mx = fmaxf(mx, __shfl_xor(mx, off));
    float p = (lane < KE) ? exp2f(1.44269504f*(sc_ - mx)) : 0.f;
    float sm = p;
    #pragma unroll
    for (int off = 32; off; off >>= 1) sm += __shfl_xor(sm, off);
    float alpha = p / sm;
    if (lane < KE){
      int k = m*KE + lane;
      int ks = k >> 5;
      int ln = m | (((k>>3)&3) << 4);
      ((unsigned short*)pF)[((ks<<6) + ln)*8 + (k&7)] = f2b(alpha);
    }
  }
  __syncthreads();

  {
    const int c = lane & 15, g = lane >> 4;
    const int d = w*16 + c;
    f32x4 acc = (f32x4){0,0,0,0};
    #pragma unroll
    for (int ks = 0; ks < 4; ++ks){
      bf16x8 A = as_bf16x8(*(const int4*)&pF[((ks<<6) + lane) << 2]);
      union { unsigned short u[8]; bf16x8 v; } bb;
      #pragma unroll
      for (int j = 0; j < 8; ++j){
        int e = ks*32 + g*8 + j;
        bb.u[j] = encL[hwaddr(e, d)];
      }
      acc = __builtin_amdgcn_mfma_f32_16x16x32_bf16(A, bb.v, acc, 0, 0, 0);
    }
    if (g == 0){
      #pragma unroll
      for (int r = 0; r < 4; ++r){
        ctx[(w*N_NODES + (n0 + r))*16 + c] = f2b(acc[r]);   // wtile-major, wave = 1 line
      }
    }
  }
}

// ---------------- K2: node update, 512 threads, NTU=40, grid 250; wtile-major bf16 state ----------------
__global__ __launch_bounds__(512) void node_update_mfma(
    const float* __restrict__ s_prev, const float* __restrict__ s0,
    const float* __restrict__ z, const unsigned short* __restrict__ ctx,
    const unsigned int* __restrict__ wp_obs, const unsigned int* __restrict__ wp_st,
    const unsigned int* __restrict__ wp_act,
    const float* __restrict__ obs_b, const float* __restrict__ st_b,
    const float* __restrict__ act_b1,
    const float* __restrict__ act_W2, const float* __restrict__ act_b2,
    const float* __restrict__ dyn_A, const float* __restrict__ dyn_B,
    unsigned short* __restrict__ oh, unsigned short* __restrict__ oc,
    unsigned short* __restrict__ sh, unsigned short* __restrict__ sc,
    float* __restrict__ u, float* __restrict__ s_next,
    unsigned short* __restrict__ snext_bf,
    float* __restrict__ out_state, float* __restrict__ out_input, int tstep)
{
  __shared__ __align__(16) union UB {
    struct { unsigned int X1[MT*NKS_O*64*4]; unsigned int X2[MT*NKS_S*64*4]; } x;
    float F[48][FC+4];
  } ubuf;
  __shared__ __align__(16) unsigned int fragX3[MT*NKS_A*64*4];
  __shared__ float sps[48][SD];
  __shared__ float u2p[48][ID][4];
  __shared__ float u2s[48][ID];

  const int tid  = threadIdx.x;
  const int n0   = blockIdx.x * NTU;
  const int w    = tid >> 6;      // 0..7
  const int lane = tid & 63;
  const int col  = lane & 15;
  const int hcol = w*16 + col;

  // ---- prefetch gate states (wtile w, coalesced lines) ----
  float ocv[MT][4], scv[MT][4];
  #pragma unroll
  for (int Mt = 0; Mt < MT; ++Mt){
    #pragma unroll
    for (int r = 0; r < 4; ++r){
      int m = Mt*16 + ((lane>>4)<<2) + r;
      int gn = n0 + m;
      ocv[Mt][r] = (m < NTU) ? b2f(oc[(w*N_NODES + gn)*16 + col]) : 0.f;
      scv[Mt][r] = (m < NTU) ? b2f(sc[(w*N_NODES + gn)*16 + col]) : 0.f;
    }
  }

  // ---- staging (48 rows, pad rows zero) ----
  for (int idx = tid; idx < 48*96; idx += 512){
    int m = idx / 96, kp = idx - m*96; int k0 = kp*2; int gn = n0 + m;
    unsigned int d = 0;
    if (m < NTU){
      if (k0 < ED) d = *(const unsigned int*)&ctx[((k0>>4)*N_NODES + gn)*16 + (k0&15)];
      else { int h = k0 - ED; d = *(const unsigned int*)&oh[((h>>4)*N_NODES + gn)*16 + (h&15)]; }
    }
    int Mt = m >> 4;
    int ln = (m & 15) | (((k0>>3)&3)<<4);
    ubuf.x.X1[(((Mt*NKS_O + (k0>>5))*64 + ln)<<2) + ((k0&7)>>1)] = d;
  }
  for (int idx = tid; idx < 48*80; idx += 512){
    int m = idx / 80, kp = idx - m*80; int k0 = kp*2; int gn = n0 + m;
    unsigned int d = 0;
    if (m < NTU){
      if (k0 < 8)        d = pack2(s_prev[gn*SD+k0]-s0[gn*SD+k0], s_prev[gn*SD+k0+1]-s0[gn*SD+k0+1]);
      else if (k0 == 8)  d = pack2(u[gn*ID], u[gn*ID+1]);
      else if (k0 < 138) { int h = k0 - 10; d = *(const unsigned int*)&sh[((h>>4)*N_NODES + gn)*16 + (h&15)]; }
    }
    int Mt = m >> 4;
    int ln = (m & 15) | (((k0>>3)&3)<<4);
    ubuf.x.X2[(((Mt*NKS_S + (k0>>5))*64 + ln)<<2) + ((k0&7)>>1)] = d;
  }
  for (int idx = tid; idx < 48*32; idx += 512){
    int m = idx / 32, p = idx - m*32; int gn = n0 + m;
    int k0 = (p < 4) ? p*2 : 256 + p*2;
    float v0 = 0.f, v1 = 0.f;
    if (m < NTU){
      if (k0 < 8){ v0 = s_prev[gn*SD+k0]-s0[gn*SD+k0]; v1 = s_prev[gn*SD+k0+1]-s0[gn*SD+k0+1]; }
      else if (k0 < 296){ v0 = z[gn*ZD + k0-264]; v1 = z[gn*ZD + k0-263]; }
    }
    int Mt = m >> 4;
    int ln = (m & 15) | (((k0>>3)&3)<<4);
    fragX3[(((Mt*NKS_A + (k0>>5))*64 + ln)<<2) + ((k0&7)>>1)] = pack2(v0, v1);
  }
  if (tid < NTU*SD){
    int m = tid >> 3, i = tid & 7;
    sps[m][i] = s_prev[(n0+m)*SD + i];
  }
  __syncthreads();

  // ---- obs LSTM: acc[Mt][g], ctile = w + 8g ----
  {
    f32x4 acc[MT][4];
    #pragma unroll
    for (int Mt = 0; Mt < MT; ++Mt)
      #pragma unroll
      for (int g = 0; g < 4; ++g){
        float b = obs_b[g*HH + hcol];
        acc[Mt][g] = (f32x4){b, b, b, b};
      }
    #pragma unroll
    for (int ks = 0; ks < NKS_O; ++ks){
      bf16x8 a[MT];
      #pragma unroll
      for (int Mt = 0; Mt < MT; ++Mt)
        a[Mt] = as_bf16x8(*(const int4*)&ubuf.x.X1[(((Mt*NKS_O + ks)*64 + lane)<<2)]);
      #pragma unroll
      for (int g = 0; g < 4; ++g){
        int c = w + 8*g;
        bf16x8 b = as_bf16x8(*(const int4*)&wp_obs[(((c*NKS_O + ks)*64 + lane)<<2)]);
        #pragma unroll
        for (int Mt = 0; Mt < MT; ++Mt)
          acc[Mt][g] = __builtin_amdgcn_mfma_f32_16x16x32_bf16(a[Mt], b, acc[Mt][g], 0, 0, 0);
      }
    }
    #pragma unroll
    for (int Mt = 0; Mt < MT; ++Mt){
      #pragma unroll
      for (int r = 0; r < 4; ++r){
        int m = Mt*16 + ((lane>>4)<<2) + r; int gn = n0 + m;
        float h2 = 0.f;
        if (m < NTU){
          float gi = acc[Mt][0][r], gf = acc[Mt][1][r], gg = acc[Mt][2][r], go = acc[Mt][3][r];
          float c2 = sigm(gf)*ocv[Mt][r] + sigm(gi)*tanh_f(gg);
          h2 = sigm(go)*tanh_f(c2);
          oc[(w*N_NODES + gn)*16 + col] = f2b(c2);
          oh[(w*N_NODES + gn)*16 + col] = f2b(h2);
        }
        int k = 8 + hcol;
        int ln = (m & 15) | (((k>>3)&3)<<4);
        ((unsigned short*)fragX3)[(((m>>4)*NKS_A + (k>>5))*64 + ln)*8 + (k&7)] = f2b(h2);
      }
    }
  }

  // ---- st LSTM ----
  {
    f32x4 acc[MT][4];
    #pragma unroll
    for (int Mt = 0; Mt < MT; ++Mt)
      #pragma unroll
      for (int g = 0; g < 4; ++g){
        float b = st_b[g*HH + hcol];
        acc[Mt][g] = (f32x4){b, b, b, b};
      }
    #pragma unroll
    for (int ks = 0; ks < NKS_S; ++ks){
      bf16x8 a[MT];
      #pragma unroll
      for (int Mt = 0; Mt < MT; ++Mt)
        a[Mt] = as_bf16x8(*(const int4*)&ubuf.x.X2[(((Mt*NKS_S + ks)*64 + lane)<<2)]);
      #pragma unroll
      for (int g = 0; g < 4; ++g){
        int c = w + 8*g;
        bf16x8 b = as_bf16x8(*(const int4*)&wp_st[(((c*NKS_S + ks)*64 + lane)<<2)]);
        #pragma unroll
        for (int Mt = 0; Mt < MT; ++Mt)
          acc[Mt][g] = __builtin_amdgcn_mfma_f32_16x16x32_bf16(a[Mt], b, acc[Mt][g], 0, 0, 0);
      }
    }
    #pragma unroll
    for (int Mt = 0; Mt < MT; ++Mt){
      #pragma unroll
      for (int r = 0; r < 4; ++r){
        int m = Mt*16 + ((lane>>4)<<2) + r; int gn = n0 + m;
        float h2 = 0.f;
        if (m < NTU){
          float gi = acc[Mt][0][r], gf = acc[Mt][1][r], gg = acc[Mt][2][r], go = acc[Mt][3][r];
          float c2 = sigm(gf)*scv[Mt][r] + sigm(gi)*tanh_f(gg);
          h2 = sigm(go)*tanh_f(c2);
          sc[(w*N_NODES + gn)*16 + col] = f2b(c2);
          sh[(w*N_NODES + gn)*16 + col] = f2b(h2);
        }
        int k = 136 + hcol;
        int ln = (m & 15) | (((k>>3)&3)<<4);
        ((unsigned short*)fragX3)[(((m>>4)*NKS_A + (k>>5))*64 + ln)*8 + (k&7)] = f2b(h2);
      }
    }
  }
  __syncthreads();   // X3 complete; X1/X2 dead -> F overlays

  // ---- act1: ctile w ----
  {
    float b1 = act_b1[hcol];
    f32x4 acc[MT];
    #pragma unroll
    for (int Mt = 0; Mt < MT; ++Mt) acc[Mt] = (f32x4){b1, b1, b1, b1};
    #pragma unroll
    for (int ks = 0; ks < NKS_A; ++ks){
      bf16x8 bb = as_bf16x8(*(const int4*)&wp_act[(((w*NKS_A + ks)*64 + lane)<<2)]);
      #pragma unroll
      for (int Mt = 0; Mt < MT; ++Mt){
        bf16x8 a = as_bf16x8(*(const int4*)&fragX3[(((Mt*NKS_A + ks)*64 + lane)<<2)]);
        acc[Mt] = __builtin_amdgcn_mfma_f32_16x16x32_bf16(a, bb, acc[Mt], 0, 0, 0);
      }
    }
    #pragma unroll
    for (int Mt = 0; Mt < MT; ++Mt){
      #pragma unroll
      for (int r = 0; r < 4; ++r){
        int m = Mt*16 + ((lane>>4)<<2) + r;
        ubuf.F[m][hcol] = fmaxf(acc[Mt][r], 0.f);
      }
    }
  }
  __syncthreads();

  // ---- act2 ----
  if (tid < 48*ID*4){
    int m  = tid >> 3;
    int c  = (tid >> 2) & 1;
    int kq = tid & 3;
    float p = 0.f;
    #pragma unroll
    for (int i = 0; i < 32; ++i){
      int j = kq*32 + i;
      p = fmaf(ubuf.F[m][j], act_W2[j*ID + c], p);
    }
    u2p[m][c][kq] = p;
  }
  __syncthreads();
  if (tid < NTU*ID){
    int m = tid >> 1, c = tid & 1; int gn = n0 + m;
    float s = act_b2[c] + u2p[m][c][0] + u2p[m][c][1] + u2p[m][c][2] + u2p[m][c][3];
    u2s[m][c] = s;
    u[gn*ID + c] = s;
    out_input[tstep*N_NODES*ID + gn*ID + c] = s;
  }
  __syncthreads();

  // ---- dynamics (also writes bf16 mirror for next edge_att gather) ----
  if (tid < NTU*SD){
    int m = tid >> 3, d = tid & 7; int gn = n0 + m;
    float acc = 0.f;
    #pragma unroll
    for (int e = 0; e < SD; ++e) acc = fmaf(sps[m][e], dyn_A[d*SD+e], acc);
    #pragma unroll
    for (int c = 0; c < ID; ++c) acc = fmaf(u2s[m][c], dyn_B[d*ID+c], acc);
    float s2v = sps[m][d] + DT_C*acc;
    s_next[gn*SD+d] = s2v;
    snext_bf[gn*SD+d] = f2b(s2v);
    out_state[tstep*N_NODES*SD + gn*SD + d] = s2v;
  }
}

extern "C" void kernel_launch(void* const* d_in, const int* in_sizes, int n_in,
                              void* d_out, int out_size, void* d_ws, size_t ws_size,
                              hipStream_t stream)
{
  const float* state_history = (const float*)d_in[0];
  const float* z        = (const float*)d_in[1];
  const int*   edge_idx1 = (const int*)d_in[2];
  const int*   edge_idx2 = (const int*)d_in[3];
  const int*   node_obs_idx = (const int*)d_in[4];
  const float* W_edge  = (const float*)d_in[5];
  const float* b_edge  = (const float*)d_in[6];
  const float* att_W1  = (const float*)d_in[7];
  const float* att_W2  = (const float*)d_in[8];
  const float* att_v   = (const float*)d_in[9];
  const float* obs_Wi  = (const float*)d_in[10];
  const float* obs_Wh  = (const float*)d_in[11];
  const float* obs_b   = (const float*)d_in[12];
  const float* st_Wi   = (const float*)d_in[13];
  const float* st_Wh   = (const float*)d_in[14];
  const float* st_b    = (const float*)d_in[15];
  const float* oh0_W   = (const float*)d_in[16];
  const float* oh0_b   = (const float*)d_in[17];
  const float* oc0_W   = (const float*)d_in[18];
  const float* oc0_b   = (const float*)d_in[19];
  const float* sh0_W   = (const float*)d_in[20];
  const float* sh0_b   = (const float*)d_in[21];
  const float* sc0_W   = (const float*)d_in[22];
  const float* sc0_b   = (const float*)d_in[23];
  const float* act_W1  = (const float*)d_in[24];
  const float* act_b1  = (const float*)d_in[25];
  const float* act_W2  = (const float*)d_in[26];
  const float* act_b2  = (const float*)d_in[27];
  const float* dyn_A   = (const float*)d_in[28];
  const float* dyn_B   = (const float*)d_in[29];

  const float* s0 = state_history + 3*N_NODES*SD;

  float* wsf = (float*)d_ws;
  float* sbuf0 = wsf;
  float* sbuf1 = sbuf0 + N_NODES*SD;
  float* u     = sbuf1 + N_NODES*SD;
  unsigned short* oh    = (unsigned short*)(u + N_NODES*ID);
  unsigned short* oc    = oh + N_NODES*HH;
  unsigned short* sh    = oc + N_NODES*HH;
  unsigned short* sc    = sh + N_NODES*HH;
  unsigned short* ctx   = sc + N_NODES*HH;
  unsigned short* s0bf  = ctx + N_NODES*ED;
  unsigned short* sbf0  = s0bf + N_NODES*SD;
  unsigned short* sbf1  = sbf0 + N_NODES*SD;
  float* sbuf[2] = { sbuf0, sbuf1 };
  unsigned short* sbf[2] = { sbf0, sbf1 };

  unsigned int* wp_obs  = (unsigned int*)(sbf1 + N_NODES*SD);
  unsigned int* wp_st   = wp_obs + WP_OBS_SZ;
  unsigned int* wp_act  = wp_st  + WP_ST_SZ;
  unsigned int* wp_edge = wp_act + WP_ACT_SZ;
  unsigned int* wp_att1 = wp_edge + WP_EDGE_SZ;

  float* out_state = (float*)d_out;
  float* out_input = out_state + FT*N_NODES*SD;

  hipLaunchKernelGGL(pack_weights, dim3(438), dim3(256), 0, stream,
      obs_Wi, obs_Wh, st_Wi, st_Wh, act_W1, W_edge, att_W1,
      wp_obs, wp_st, wp_act, wp_edge, wp_att1);

  hipLaunchKernelGGL(init_kernel, dim3((N_NODES*HH+255)/256), dim3(256), 0, stream,
      s0, oh0_W, oh0_b, oc0_W, oc0_b, sh0_W, sh0_b, sc0_W, sc0_b, oh, oc, sh, sc, u, s0bf);

  for (int t = 0; t < FT; ++t){
    const float* s_prev = (t==0) ? s0 : sbuf[(t-1)&1];
    const unsigned short* sprev_bf = (t==0) ? s0bf : sbf[(t-1)&1];
    float* s_next = sbuf[t&1];
    unsigned short* snext_bf = sbf[t&1];
    hipLaunchKernelGGL(edge_att_mfma, dim3(N_NODES/NB), dim3(256), 0, stream,
        s_prev, s0, sprev_bf, edge_idx1, edge_idx2, node_obs_idx,
        wp_edge, wp_att1, b_edge, att_W2, att_v, ctx);
    hipLaunchKernelGGL(node_update_mfma, dim3(N_NODES/NTU), dim3(512), 0, stream,
        s_prev, s0, z, ctx,
        wp_obs, wp_st, wp_act,
        obs_b, st_b, act_b1, act_W2, act_b2, dyn_A, dyn_B,
        oh, oc, sh, sc, u, s_next, snext_bf, out_state, out_input, t);
  }
}

// Round 23
// 306.887 us; speedup vs baseline: 1.0393x; 1.0393x over previous
//
#include <hip/hip_runtime.h>
#include <hip/hip_bf16.h>
#include <math.h>

#define N_NODES 10000
#define KE 31
#define SD 8
#define ID 2
#define ZD 32
#define ED 64
#define HH 128
#define FC 128
#define AT 16
#define FT 6
#define DT_C 0.25f
#define NB 4           // nodes per edge_att block

#define NTU 40         // real nodes per node_update block: grid = 250
#define MT 3           // M-tiles (48 rows, 8 pad)
#define NWV 12         // waves per node_update block (768 threads, 3/SIMD)

#define NKS_O 6        // obs LSTM K=192 = 6*32
#define NKS_S 5        // st LSTM  K=160 = 5*32
#define NKS_A 10       // act1     K=320 = 10*32

// packed-weight sizes (uints)
#define WP_OBS_SZ 49152
#define WP_ST_SZ  40960
#define WP_ACT_SZ 20480
#define WP_EDGE_SZ 1024
#define WP_ATT1_SZ 512

typedef __bf16 bf16x8 __attribute__((ext_vector_type(8)));
typedef float  f32x4  __attribute__((ext_vector_type(4)));

__device__ __forceinline__ float sigm(float x){ return 1.0f/(1.0f+exp2f(-1.44269504f*x)); }
__device__ __forceinline__ float tanh_f(float x){ return 1.0f - 2.0f/(1.0f+exp2f(2.88539008f*x)); }

__device__ __forceinline__ unsigned short f2b(float f){
  __hip_bfloat16 h = __float2bfloat16(f);
  return __builtin_bit_cast(unsigned short, h);
}
__device__ __forceinline__ float b2f(unsigned short x){
  unsigned int u = ((unsigned int)x) << 16;
  return __builtin_bit_cast(float, u);
}
__device__ __forceinline__ unsigned int pack2(float a, float b){
  return (unsigned int)f2b(a) | ((unsigned int)f2b(b) << 16);
}
__device__ __forceinline__ bf16x8 as_bf16x8(int4 v){
  union { int4 i; bf16x8 b; } u; u.i = v; return u.b;
}
__device__ __forceinline__ int hwaddr(int e, int d){
  return e*64 + ((((d>>3)<<3) ^ ((e&7)<<3)) + (d&7));
}

// ---------------- pack_weights (unchanged layout) ----------------
__global__ __launch_bounds__(256) void pack_weights(
    const float* __restrict__ obs_Wi, const float* __restrict__ obs_Wh,
    const float* __restrict__ st_Wi,  const float* __restrict__ st_Wh,
    const float* __restrict__ act_W1, const float* __restrict__ W_edge,
    const float* __restrict__ att_W1,
    unsigned int* __restrict__ wp_obs, unsigned int* __restrict__ wp_st,
    unsigned int* __restrict__ wp_act, unsigned int* __restrict__ wp_edge,
    unsigned int* __restrict__ wp_att1)
{
  int t = blockIdx.x*256 + threadIdx.x;
  if (t < 49152){
    int c = t / 1536; int r = t - c*1536;
    int ks = r >> 8; int q = r & 255;
    int ln = q >> 2; int dw = q & 3;
    int k  = ks*32 + ((ln>>4)<<3) + dw*2;
    int col = (c<<4) + (ln & 15);
    float v0 = (k   < 64) ? obs_Wi[k*4*HH + col]      : obs_Wh[(k-64)*4*HH + col];
    float v1 = (k+1 < 64) ? obs_Wi[(k+1)*4*HH + col]  : obs_Wh[(k-63)*4*HH + col];
    wp_obs[t] = pack2(v0, v1);
  } else if (t < 90112){
    int t2 = t - 49152;
    int c = t2 / 1280; int r = t2 - c*1280;
    int ks = r >> 8; int q = r & 255;
    int ln = q >> 2; int dw = q & 3;
    int k  = ks*32 + ((ln>>4)<<3) + dw*2;
    int col = (c<<4) + (ln & 15);
    float v0, v1;
    { int kk=k;   v0 = (kk<10)? st_Wi[kk*4*HH+col] : (kk<138 ? st_Wh[(kk-10)*4*HH+col] : 0.f); }
    { int kk=k+1; v1 = (kk<10)? st_Wi[kk*4*HH+col] : (kk<138 ? st_Wh[(kk-10)*4*HH+col] : 0.f); }
    wp_st[t2] = pack2(v0, v1);
  } else if (t < 110592){
    int t3 = t - 90112;
    int c = t3 / 2560; int r = t3 - c*2560;
    int ks = r >> 8; int q = r & 255;
    int ln = q >> 2; int dw = q & 3;
    int k  = ks*32 + ((ln>>4)<<3) + dw*2;
    int col = (c<<4) + (ln & 15);
    float v0 = (k   < 296) ? act_W1[k*FC + col]     : 0.f;
    float v1 = (k+1 < 296) ? act_W1[(k+1)*FC + col] : 0.f;
    wp_act[t3] = pack2(v0, v1);
  } else if (t < 111616){
    int t4 = t - 110592;
    int c = t4 >> 8; int r = t4 & 255;
    int ln = r >> 2; int dw = r & 3;
    int k  = ((ln>>4)<<3) + dw*2;
    int col = (c<<4) + (ln & 15);
    float v0 = (k   < 16) ? W_edge[k*ED + col]     : 0.f;
    float v1 = (k+1 < 16) ? W_edge[(k+1)*ED + col] : 0.f;
    wp_edge[t4] = pack2(v0, v1);
  } else if (t < 112128){
    int t5 = t - 111616;
    int ks = t5 >> 8; int r = t5 & 255;
    int ln = r >> 2; int dw = r & 3;
    int k  = ks*32 + ((ln>>4)<<3) + dw*2;
    int col = ln & 15;
    float v0 = (k   < 64) ? att_W1[k*AT + col]     : 0.f;
    float v1 = (k+1 < 64) ? att_W1[(k+1)*AT + col] : 0.f;
    wp_att1[t5] = pack2(v0, v1);
  }
}

// ---------------- init: states bf16; also mirror s0 as bf16 ----------------
__global__ __launch_bounds__(256) void init_kernel(
    const float* __restrict__ s0,
    const float* __restrict__ oh0_W, const float* __restrict__ oh0_b,
    const float* __restrict__ oc0_W, const float* __restrict__ oc0_b,
    const float* __restrict__ sh0_W, const float* __restrict__ sh0_b,
    const float* __restrict__ sc0_W, const float* __restrict__ sc0_b,
    unsigned short* __restrict__ oh, unsigned short* __restrict__ oc,
    unsigned short* __restrict__ sh, unsigned short* __restrict__ sc,
    float* __restrict__ u, unsigned short* __restrict__ s0bf)
{
  int t = blockIdx.x*256 + threadIdx.x;
  if (t < N_NODES*ID) u[t] = 0.0f;
  if (t < N_NODES*SD) s0bf[t] = f2b(s0[t]);
  if (t >= N_NODES*HH) return;
  int n = t >> 7, j = t & 127;
  float s[SD];
  #pragma unroll
  for (int i=0;i<SD;i++) s[i] = s0[n*SD+i];
  float a0=oh0_b[j], a1=oc0_b[j], a2=sh0_b[j], a3=sc0_b[j];
  #pragma unroll
  for (int i=0;i<SD;i++){
    a0 = fmaf(s[i], oh0_W[i*HH+j], a0);
    a1 = fmaf(s[i], oc0_W[i*HH+j], a1);
    a2 = fmaf(s[i], sh0_W[i*HH+j], a2);
    a3 = fmaf(s[i], sc0_W[i*HH+j], a3);
  }
  oh[t]=f2b(a0); oc[t]=f2b(a1); sh[t]=f2b(a2); sc[t]=f2b(a3);
}

// ---------------- K1: edge encode + attention; endpoint gather bf16 ----------------
__global__ __launch_bounds__(256) void edge_att_mfma(
    const float* __restrict__ s_prev, const float* __restrict__ s0,
    const unsigned short* __restrict__ sprev_bf,
    const int* __restrict__ edge_idx1, const int* __restrict__ edge_idx2,
    const int* __restrict__ node_obs_idx,
    const unsigned int* __restrict__ wp_edge, const unsigned int* __restrict__ wp_att1,
    const float* __restrict__ b_edge, const float* __restrict__ att_W2,
    const float* __restrict__ att_v, unsigned short* __restrict__ ctx)
{
  __shared__ __align__(16) unsigned int eF[8*64*4];
  __shared__ __align__(16) unsigned short encL[128*64];
  __shared__ __align__(16) unsigned int pF[4*64*4];
  __shared__ float scores[128];
  __shared__ float relbuf[NB][SD];
  __shared__ float relW2b[NB][AT];
  __shared__ unsigned char emask[128];

  const int tid  = threadIdx.x;
  const int lane = tid & 63;
  const int w    = tid >> 6;
  const int n0   = blockIdx.x * NB;
  const int EPB  = NB*KE;

  {
    ((uint4*)pF)[tid] = (uint4){0,0,0,0};
    int eb  = tid >> 1;
    int khi = tid & 1;
    int valid = 0;
    uint4 d = (uint4){0,0,0,0};
    if (eb < EPB){
      int nl = eb / KE;
      int j  = eb - nl*KE;
      int idx = node_obs_idx[(n0+nl)*KE + j];
      if (idx > 0){
        valid = 1;
        int e = idx - 1;
        int i = khi ? edge_idx2[e] : edge_idx1[e];
        d = *(const uint4*)&sprev_bf[i*SD];
      }
    }
    int mt = eb >> 4;
    int base = ((mt<<6) + (eb&15) + (khi<<4)) << 2;
    ((uint4*)&eF[base])[0] = d;
    int zbase = ((mt<<6) + (eb&15) + ((khi+2)<<4)) << 2;
    ((uint4*)&eF[zbase])[0] = (uint4){0,0,0,0};
    if (khi == 0) emask[eb] = (unsigned char)valid;
    if (tid < NB*SD){
      int m = tid >> 3, i = tid & 7;
      relbuf[m][i] = s_prev[(n0+m)*SD + i] - s0[(n0+m)*SD + i];
    }
  }
  __syncthreads();

  if (tid < NB*AT){
    int m = tid >> 4, a = tid & 15;
    float acc = 0.f;
    #pragma unroll
    for (int i = 0; i < SD; ++i) acc = fmaf(relbuf[m][i], att_W2[i*AT + a], acc);
    relW2b[m][a] = acc;
  }
  {
    const int c = lane & 15, g = lane >> 4;
    #pragma unroll
    for (int q = 0; q < 2; ++q){
      int mt = w*2 + q;
      bf16x8 A = as_bf16x8(*(const int4*)&eF[((mt<<6) + lane) << 2]);
      f32x4 acc[4];
      #pragma unroll
      for (int ct = 0; ct < 4; ++ct){
        bf16x8 B = as_bf16x8(*(const int4*)&wp_edge[((ct<<6) + lane) << 2]);
        acc[ct] = (f32x4){0,0,0,0};
        acc[ct] = __builtin_amdgcn_mfma_f32_16x16x32_bf16(A, B, acc[ct], 0, 0, 0);
      }
      #pragma unroll
      for (int ct = 0; ct < 4; ++ct){
        int d = ct*16 + c;
        float bias = b_edge[d];
        #pragma unroll
        for (int r = 0; r < 4; ++r){
          int eb = mt*16 + g*4 + r;
          float v = acc[ct][r] + bias;
          v = emask[eb] ? fmaxf(v, 0.f) : 0.f;
          encL[hwaddr(eb, d)] = f2b(v);
        }
      }
    }
  }
  __syncthreads();

  {
    const int c = lane & 15, g = lane >> 4;
    const float av = att_v[c];
    #pragma unroll
    for (int q = 0; q < 2; ++q){
      int mt = w*2 + q;
      int row = mt*16 + c;
      f32x4 acc = (f32x4){0,0,0,0};
      #pragma unroll
      for (int ks = 0; ks < 2; ++ks){
        int hw = row*64 + (((ks*4 + g) << 3) ^ ((row&7) << 3));
        bf16x8 A = *(const bf16x8*)&encL[hw];
        bf16x8 B = as_bf16x8(*(const int4*)&wp_att1[((ks<<6) + lane) << 2]);
        acc = __builtin_amdgcn_mfma_f32_16x16x32_bf16(A, B, acc, 0, 0, 0);
      }
      #pragma unroll
      for (int r = 0; r < 4; ++r){
        int eb = mt*16 + g*4 + r;
        int nm = eb / KE; if (nm > NB-1) nm = NB-1;
        float sv = av * tanh_f(acc[r] + relW2b[nm][c]);
        #pragma unroll
        for (int off = 1; off < 16; off <<= 1) sv += __shfl_xor(sv, off);
        if (c == 0 && eb < EPB) scores[eb] = sv;
      }
    }
  }
  __syncthreads();

  {
    int m = w;
    float sc_ = (lane < KE) ? scores[m*KE + lane] : -INFINITY;
    float mx = sc_;
    #pragma unroll
    for (int off = 32; off; off >>= 1) mx = fmaxf(mx, __shfl_xor(mx, off));
    float p = (lane < KE) ? exp2f(1.44269504f*(sc_ - mx)) : 0.f;
    float sm = p;
    #pragma unroll
    for (int off = 32; off; off >>= 1) sm += __shfl_xor(sm, off);
    float alpha = p / sm;
    if (lane < KE){
      int k = m*KE + lane;
      int ks = k >> 5;
      int ln = m | (((k>>3)&3) << 4);
      ((unsigned short*)pF)[((ks<<6) + ln)*8 + (k&7)] = f2b(alpha);
    }
  }
  __syncthreads();

  {
    const int c = lane & 15, g = lane >> 4;
    const int d = w*16 + c;
    f32x4 acc = (f32x4){0,0,0,0};
    #pragma unroll
    for (int ks = 0; ks < 4; ++ks){
      bf16x8 A = as_bf16x8(*(const int4*)&pF[((ks<<6) + lane) << 2]);
      union { unsigned short u[8]; bf16x8 v; } bb;
      #pragma unroll
      for (int j = 0; j < 8; ++j){
        int e = ks*32 + g*8 + j;
        bb.u[j] = encL[hwaddr(e, d)];
      }
      acc = __builtin_amdgcn_mfma_f32_16x16x32_bf16(A, bb.v, acc, 0, 0, 0);
    }
    if (g == 0){
      #pragma unroll
      for (int r = 0; r < 4; ++r){
        ctx[(n0 + r)*ED + d] = f2b(acc[r]);
      }
    }
  }
}

// ---------------- K2: node update, 768 threads (12 waves = 3/SIMD), NTU=40, grid 250 ----------------
// 24 work units (Mt,ct); wave w handles units {w, w+12}. Weights read once per block.
__global__ __launch_bounds__(768) void node_update_mfma(
    const float* __restrict__ s_prev, const float* __restrict__ s0,
    const float* __restrict__ z, const unsigned short* __restrict__ ctx,
    const unsigned int* __restrict__ wp_obs, const unsigned int* __restrict__ wp_st,
    const unsigned int* __restrict__ wp_act,
    const float* __restrict__ obs_b, const float* __restrict__ st_b,
    const float* __restrict__ act_b1,
    const float* __restrict__ act_W2, const float* __restrict__ act_b2,
    const float* __restrict__ dyn_A, const float* __restrict__ dyn_B,
    unsigned short* __restrict__ oh, unsigned short* __restrict__ oc,
    unsigned short* __restrict__ sh, unsigned short* __restrict__ sc,
    float* __restrict__ u, float* __restrict__ s_next,
    unsigned short* __restrict__ snext_bf,
    float* __restrict__ out_state, float* __restrict__ out_input, int tstep)
{
  __shared__ __align__(16) union UB {
    struct { unsigned int X1[MT*NKS_O*64*4]; unsigned int X2[MT*NKS_S*64*4]; } x;
    float F[48][FC+4];
  } ubuf;
  __shared__ __align__(16) unsigned int fragX3[MT*NKS_A*64*4];
  __shared__ float sps[48][SD];
  __shared__ float u2p[48][ID][4];
  __shared__ float u2s[48][ID];

  const int tid  = threadIdx.x;
  const int n0   = blockIdx.x * NTU;
  const int w    = tid >> 6;      // 0..11
  const int lane = tid & 63;

  // ---- prefetch gate states for this wave's 2 units ----
  float ocv[2][4], scv[2][4];
  #pragma unroll
  for (int s = 0; s < 2; ++s){
    int uq = w + NWV*s;             // unit 0..23
    int Mt = uq >> 3, ct = uq & 7;
    int hc = ct*16 + (lane & 15);
    #pragma unroll
    for (int r = 0; r < 4; ++r){
      int m = Mt*16 + ((lane>>4)<<2) + r;
      int gn = n0 + m;
      ocv[s][r] = (m < NTU) ? b2f(oc[gn*HH + hc]) : 0.f;
      scv[s][r] = (m < NTU) ? b2f(sc[gn*HH + hc]) : 0.f;
    }
  }

  // ---- staging (48 rows, pad rows zero) ----
  for (int idx = tid; idx < 48*96; idx += 768){
    int m = idx / 96, kp = idx - m*96; int k0 = kp*2; int gn = n0 + m;
    unsigned int d = 0;
    if (m < NTU){
      if (k0 < ED) d = *(const unsigned int*)&ctx[gn*ED + k0];
      else         d = *(const unsigned int*)&oh[gn*HH + k0 - ED];
    }
    int Mt = m >> 4;
    int ln = (m & 15) | (((k0>>3)&3)<<4);
    ubuf.x.X1[(((Mt*NKS_O + (k0>>5))*64 + ln)<<2) + ((k0&7)>>1)] = d;
  }
  for (int idx = tid; idx < 48*80; idx += 768){
    int m = idx / 80, kp = idx - m*80; int k0 = kp*2; int gn = n0 + m;
    unsigned int d = 0;
    if (m < NTU){
      if (k0 < 8)        d = pack2(s_prev[gn*SD+k0]-s0[gn*SD+k0], s_prev[gn*SD+k0+1]-s0[gn*SD+k0+1]);
      else if (k0 == 8)  d = pack2(u[gn*ID], u[gn*ID+1]);
      else if (k0 < 138) d = *(const unsigned int*)&sh[gn*HH + k0 - 10];
    }
    int Mt = m >> 4;
    int ln = (m & 15) | (((k0>>3)&3)<<4);
    ubuf.x.X2[(((Mt*NKS_S + (k0>>5))*64 + ln)<<2) + ((k0&7)>>1)] = d;
  }
  for (int idx = tid; idx < 48*32; idx += 768){
    int m = idx / 32, p = idx - m*32; int gn = n0 + m;
    int k0 = (p < 4) ? p*2 : 256 + p*2;
    float v0 = 0.f, v1 = 0.f;
    if (m < NTU){
      if (k0 < 8){ v0 = s_prev[gn*SD+k0]-s0[gn*SD+k0]; v1 = s_prev[gn*SD+k0+1]-s0[gn*SD+k0+1]; }
      else if (k0 < 296){ v0 = z[gn*ZD + k0-264]; v1 = z[gn*ZD + k0-263]; }
    }
    int Mt = m >> 4;
    int ln = (m & 15) | (((k0>>3)&3)<<4);
    fragX3[(((Mt*NKS_A + (k0>>5))*64 + ln)<<2) + ((k0&7)>>1)] = pack2(v0, v1);
  }
  if (tid < NTU*SD){
    int m = tid >> 3, i = tid & 7;
    sps[m][i] = s_prev[(n0+m)*SD + i];
  }
  __syncthreads();

  // ---- obs LSTM: per unit (Mt, ct), ctile = ct + 8g ----
  #pragma unroll
  for (int s = 0; s < 2; ++s){
    int uq = w + NWV*s;
    int Mt = uq >> 3, ct = uq & 7;
    int hc = ct*16 + (lane & 15);
    f32x4 acc[4];
    #pragma unroll
    for (int g = 0; g < 4; ++g){
      float b = obs_b[g*HH + hc];
      acc[g] = (f32x4){b, b, b, b};
    }
    #pragma unroll
    for (int ks = 0; ks < NKS_O; ++ks){
      bf16x8 a = as_bf16x8(*(const int4*)&ubuf.x.X1[(((Mt*NKS_O + ks)*64 + lane)<<2)]);
      #pragma unroll
      for (int g = 0; g < 4; ++g){
        int c = ct + 8*g;
        bf16x8 b = as_bf16x8(*(const int4*)&wp_obs[(((c*NKS_O + ks)*64 + lane)<<2)]);
        acc[g] = __builtin_amdgcn_mfma_f32_16x16x32_bf16(a, b, acc[g], 0, 0, 0);
      }
    }
    #pragma unroll
    for (int r = 0; r < 4; ++r){
      int m = Mt*16 + ((lane>>4)<<2) + r; int gn = n0 + m;
      float h2 = 0.f;
      if (m < NTU){
        float gi = acc[0][r], gf = acc[1][r], gg = acc[2][r], go = acc[3][r];
        float c2 = sigm(gf)*ocv[s][r] + sigm(gi)*tanh_f(gg);
        h2 = sigm(go)*tanh_f(c2);
        oc[gn*HH + hc] = f2b(c2);
        oh[gn*HH + hc] = f2b(h2);
      }
      int k = 8 + hc;
      int ln = (m & 15) | (((k>>3)&3)<<4);
      ((unsigned short*)fragX3)[(((m>>4)*NKS_A + (k>>5))*64 + ln)*8 + (k&7)] = f2b(h2);
    }
  }

  // ---- st LSTM: per unit ----
  #pragma unroll
  for (int s = 0; s < 2; ++s){
    int uq = w + NWV*s;
    int Mt = uq >> 3, ct = uq & 7;
    int hc = ct*16 + (lane & 15);
    f32x4 acc[4];
    #pragma unroll
    for (int g = 0; g < 4; ++g){
      float b = st_b[g*HH + hc];
      acc[g] = (f32x4){b, b, b, b};
    }
    #pragma unroll
    for (int ks = 0; ks < NKS_S; ++ks){
      bf16x8 a = as_bf16x8(*(const int4*)&ubuf.x.X2[(((Mt*NKS_S + ks)*64 + lane)<<2)]);
      #pragma unroll
      for (int g = 0; g < 4; ++g){
        int c = ct + 8*g;
        bf16x8 b = as_bf16x8(*(const int4*)&wp_st[(((c*NKS_S + ks)*64 + lane)<<2)]);
        acc[g] = __builtin_amdgcn_mfma_f32_16x16x32_bf16(a, b, acc[g], 0, 0, 0);
      }
    }
    #pragma unroll
    for (int r = 0; r < 4; ++r){
      int m = Mt*16 + ((lane>>4)<<2) + r; int gn = n0 + m;
      float h2 = 0.f;
      if (m < NTU){
        float gi = acc[0][r], gf = acc[1][r], gg = acc[2][r], go = acc[3][r];
        float c2 = sigm(gf)*scv[s][r] + sigm(gi)*tanh_f(gg);
        h2 = sigm(go)*tanh_f(c2);
        sc[gn*HH + hc] = f2b(c2);
        sh[gn*HH + hc] = f2b(h2);
      }
      int k = 136 + hc;
      int ln = (m & 15) | (((k>>3)&3)<<4);
      ((unsigned short*)fragX3)[(((m>>4)*NKS_A + (k>>5))*64 + ln)*8 + (k&7)] = f2b(h2);
    }
  }
  __syncthreads();   // X3 complete; X1/X2 dead -> F overlays

  // ---- act1: per unit (Mt, ct) ----
  #pragma unroll
  for (int s = 0; s < 2; ++s){
    int uq = w + NWV*s;
    int Mt = uq >> 3, ct = uq & 7;
    int hc = ct*16 + (lane & 15);
    float b1 = act_b1[hc];
    f32x4 acc = (f32x4){b1, b1, b1, b1};
    #pragma unroll
    for (int ks = 0; ks < NKS_A; ++ks){
      bf16x8 bb = as_bf16x8(*(const int4*)&wp_act[(((ct*NKS_A + ks)*64 + lane)<<2)]);
      bf16x8 a = as_bf16x8(*(const int4*)&fragX3[(((Mt*NKS_A + ks)*64 + lane)<<2)]);
      acc = __builtin_amdgcn_mfma_f32_16x16x32_bf16(a, bb, acc, 0, 0, 0);
    }
    #pragma unroll
    for (int r = 0; r < 4; ++r){
      int m = Mt*16 + ((lane>>4)<<2) + r;
      ubuf.F[m][hc] = fmaxf(acc[r], 0.f);
    }
  }
  __syncthreads();

  // ---- act2 ----
  if (tid < 48*ID*4){
    int m  = tid >> 3;
    int c  = (tid >> 2) & 1;
    int kq = tid & 3;
    float p = 0.f;
    #pragma unroll
    for (int i = 0; i < 32; ++i){
      int j = kq*32 + i;
      p = fmaf(ubuf.F[m][j], act_W2[j*ID + c], p);
    }
    u2p[m][c][kq] = p;
  }
  __syncthreads();
  if (tid < NTU*ID){
    int m = tid >> 1, c = tid & 1; int gn = n0 + m;
    float s = act_b2[c] + u2p[m][c][0] + u2p[m][c][1] + u2p[m][c][2] + u2p[m][c][3];
    u2s[m][c] = s;
    u[gn*ID + c] = s;
    out_input[tstep*N_NODES*ID + gn*ID + c] = s;
  }
  __syncthreads();

  // ---- dynamics (also writes bf16 mirror for next edge_att gather) ----
  if (tid < NTU*SD){
    int m = tid >> 3, d = tid & 7; int gn = n0 + m;
    float acc = 0.f;
    #pragma unroll
    for (int e = 0; e < SD; ++e) acc = fmaf(sps[m][e], dyn_A[d*SD+e], acc);
    #pragma unroll
    for (int c = 0; c < ID; ++c) acc = fmaf(u2s[m][c], dyn_B[d*ID+c], acc);
    float s2v = sps[m][d] + DT_C*acc;
    s_next[gn*SD+d] = s2v;
    snext_bf[gn*SD+d] = f2b(s2v);
    out_state[tstep*N_NODES*SD + gn*SD + d] = s2v;
  }
}

extern "C" void kernel_launch(void* const* d_in, const int* in_sizes, int n_in,
                              void* d_out, int out_size, void* d_ws, size_t ws_size,
                              hipStream_t stream)
{
  const float* state_history = (const float*)d_in[0];
  const float* z        = (const float*)d_in[1];
  const int*   edge_idx1 = (const int*)d_in[2];
  const int*   edge_idx2 = (const int*)d_in[3];
  const int*   node_obs_idx = (const int*)d_in[4];
  const float* W_edge  = (const float*)d_in[5];
  const float* b_edge  = (const float*)d_in[6];
  const float* att_W1  = (const float*)d_in[7];
  const float* att_W2  = (const float*)d_in[8];
  const float* att_v   = (const float*)d_in[9];
  const float* obs_Wi  = (const float*)d_in[10];
  const float* obs_Wh  = (const float*)d_in[11];
  const float* obs_b   = (const float*)d_in[12];
  const float* st_Wi   = (const float*)d_in[13];
  const float* st_Wh   = (const float*)d_in[14];
  const float* st_b    = (const float*)d_in[15];
  const float* oh0_W   = (const float*)d_in[16];
  const float* oh0_b   = (const float*)d_in[17];
  const float* oc0_W   = (const float*)d_in[18];
  const float* oc0_b   = (const float*)d_in[19];
  const float* sh0_W   = (const float*)d_in[20];
  const float* sh0_b   = (const float*)d_in[21];
  const float* sc0_W   = (const float*)d_in[22];
  const float* sc0_b   = (const float*)d_in[23];
  const float* act_W1  = (const float*)d_in[24];
  const float* act_b1  = (const float*)d_in[25];
  const float* act_W2  = (const float*)d_in[26];
  const float* act_b2  = (const float*)d_in[27];
  const float* dyn_A   = (const float*)d_in[28];
  const float* dyn_B   = (const float*)d_in[29];

  const float* s0 = state_history + 3*N_NODES*SD;

  float* wsf = (float*)d_ws;
  float* sbuf0 = wsf;
  float* sbuf1 = sbuf0 + N_NODES*SD;
  float* u     = sbuf1 + N_NODES*SD;
  unsigned short* oh    = (unsigned short*)(u + N_NODES*ID);
  unsigned short* oc    = oh + N_NODES*HH;
  unsigned short* sh    = oc + N_NODES*HH;
  unsigned short* sc    = sh + N_NODES*HH;
  unsigned short* ctx   = sc + N_NODES*HH;
  unsigned short* s0bf  = ctx + N_NODES*ED;
  unsigned short* sbf0  = s0bf + N_NODES*SD;
  unsigned short* sbf1  = sbf0 + N_NODES*SD;
  float* sbuf[2] = { sbuf0, sbuf1 };
  unsigned short* sbf[2] = { sbf0, sbf1 };

  unsigned int* wp_obs  = (unsigned int*)(sbf1 + N_NODES*SD);
  unsigned int* wp_st   = wp_obs + WP_OBS_SZ;
  unsigned int* wp_act  = wp_st  + WP_ST_SZ;
  unsigned int* wp_edge = wp_act + WP_ACT_SZ;
  unsigned int* wp_att1 = wp_edge + WP_EDGE_SZ;

  float* out_state = (float*)d_out;
  float* out_input = out_state + FT*N_NODES*SD;

  hipLaunchKernelGGL(pack_weights, dim3(438), dim3(256), 0, stream,
      obs_Wi, obs_Wh, st_Wi, st_Wh, act_W1, W_edge, att_W1,
      wp_obs, wp_st, wp_act, wp_edge, wp_att1);

  hipLaunchKernelGGL(init_kernel, dim3((N_NODES*HH+255)/256), dim3(256), 0, stream,
      s0, oh0_W, oh0_b, oc0_W, oc0_b, sh0_W, sh0_b, sc0_W, sc0_b, oh, oc, sh, sc, u, s0bf);

  for (int t = 0; t < FT; ++t){
    const float* s_prev = (t==0) ? s0 : sbuf[(t-1)&1];
    const unsigned short* sprev_bf = (t==0) ? s0bf : sbf[(t-1)&1];
    float* s_next = sbuf[t&1];
    unsigned short* snext_bf = sbf[t&1];
    hipLaunchKernelGGL(edge_att_mfma, dim3(N_NODES/NB), dim3(256), 0, stream,
        s_prev, s0, sprev_bf, edge_idx1, edge_idx2, node_obs_idx,
        wp_edge, wp_att1, b_edge, att_W2, att_v, ctx);
    hipLaunchKernelGGL(node_update_mfma, dim3(N_NODES/NTU), dim3(768), 0, stream,
        s_prev, s0, z, ctx,
        wp_obs, wp_st, wp_act,
        obs_b, st_b, act_b1, act_W2, act_b2, dyn_A, dyn_B,
        oh, oc, sh, sc, u, s_next, snext_bf, out_state, out_input, t);
  }
}